// Round 6
// baseline (256.617 us; speedup 1.0000x reference)
//
#include <hip/hip_runtime.h>

#define NN 2048
#define KTOP 256
#define WIN 0.25f          // value-space window; 1000*WIN^2 = 62.5 nats = 90 bits
#define KE 1442.6951f      // 1000 * log2(e): exp(-1000 d^2) = 2^(-KE d^2)
#define LN2 0.69314718f
#define MARG2 0.0625f      // value^2 margin for top-K numerator window
#define OPB 64             // outputs per block per phase
#define BPB 32             // blocks per batch

// ---------------------------------------------------------------------------
// Per-batch software barrier. Safe because:
//  - cooperative launch guarantees all 1024 blocks co-resident (spin is safe)
//  - __syncthreads() drains every wave's global writes to the XCD L2
//    (compiler emits s_waitcnt vmcnt(0) before s_barrier)
//  - thread0's release __threadfence() emits buffer_wbl2 sc1: flushes the
//    whole L2 (cache-level op -> covers all waves' completed writes)
//  - acquire __threadfence() after the spin emits buffer_inv sc1 before any
//    dependent read -> no stale cross-XCD L2 lines
//  - counters are zeroed per launch and targets are monotone (32*phase):
//    a block reaches barrier p only after all peers passed p-1 -> no deadlock.
// ---------------------------------------------------------------------------
__device__ __forceinline__ void batch_barrier(int* bar, int target) {
    __syncthreads();
    if (threadIdx.x == 0) {
        __threadfence();   // release: wbL2
        __hip_atomic_fetch_add(bar, 1, __ATOMIC_RELAXED, __HIP_MEMORY_SCOPE_AGENT);
        while (__hip_atomic_load(bar, __ATOMIC_RELAXED, __HIP_MEMORY_SCOPE_AGENT) < target)
            __builtin_amdgcn_s_sleep(1);
        __threadfence();   // acquire: invL2
    }
    __syncthreads();
}

// ---------------------------------------------------------------------------
// Potential phase body: pout[o] = (t_o, -log2 sum_j 2^(-KE*(t_o-t_j)^2 + y_j))
// for the block's 64 consecutive sorted outputs. Union window split across
// the 4 waves; all lp reads wave-broadcast (conflict-free).
// ---------------------------------------------------------------------------
__device__ __forceinline__ void pot_phase(const float2* __restrict__ pin,
                                          float2* __restrict__ pout,
                                          float2* lp, float (*part)[OPB],
                                          int b, int chunk) {
    const int tid = threadIdx.x;
    const int w = tid >> 6, ln = tid & 63;
    const float4* src4 = (const float4*)(pin + (size_t)b * NN);
    float4* lp4 = (float4*)lp;
    for (int k = tid; k < NN / 2; k += 256) lp4[k] = src4[k];
    __syncthreads();
    const int obase = chunk << 6;
    const int o = obase + ln;
    const float x = lp[o].x;
    const float bhi = lp[obase].x + WIN;
    const float blo = lp[obase + OPB - 1].x - WIN;
    int l0 = 0, r0 = NN, l1 = 0, r1 = NN;
#pragma unroll
    for (int it = 0; it < 11; ++it) {
        int m0 = (l0 + r0) >> 1; bool c0 = lp[m0].x < bhi;  r0 = c0 ? m0 : r0; l0 = c0 ? l0 : m0 + 1;
        int m1 = (l1 + r1) >> 1; bool c1 = lp[m1].x <= blo; r1 = c1 ? m1 : r1; l1 = c1 ? l1 : m1 + 1;
    }
    const int lo = l0, hi = l1;
    float a0 = 0.f, a1 = 0.f;
    int j = lo + w;
    for (; j + 4 < hi; j += 8) {
        float2 p0 = lp[j], p1 = lp[j + 4];
        float d0 = x - p0.x, d1 = x - p1.x;
        a0 += exp2f(fmaf(-KE * d0, d0, p0.y));
        a1 += exp2f(fmaf(-KE * d1, d1, p1.y));
    }
    if (j < hi) { float2 p = lp[j]; float d = x - p.x; a0 += exp2f(fmaf(-KE * d, d, p.y)); }
    part[w][ln] = a0 + a1;
    __syncthreads();
    if (w == 0) {
        float a = (part[0][ln] + part[1][ln]) + (part[2][ln] + part[3][ln]);
        pout[(size_t)b * NN + o] = make_float2(x, -log2f(a));
    }
}

// ---------------------------------------------------------------------------
// Fused kernel: sort -> c -> r -> cc -> topk with per-batch barriers.
// ---------------------------------------------------------------------------
__global__ __launch_bounds__(256) void fused_k(const float* __restrict__ s,
                                               float2* __restrict__ A,
                                               float2* __restrict__ B,
                                               int* __restrict__ iperm,
                                               int* __restrict__ barx,
                                               float* __restrict__ out) {
    __shared__ float2 lp[NN];            // 16 KB; sort aliases as float[2048]
    __shared__ float pd[4][OPB];
    __shared__ float pn[4][OPB];
    __shared__ float pm[4][OPB];

    const int b = blockIdx.x >> 5;       // batch
    const int chunk = blockIdx.x & 31;   // 64-output chunk within batch
    const int tid = threadIdx.x;
    int* bar = barx + b * 32;            // 128B-padded per-batch counter

    // ---------------- phase 0: rank sort (64 elems/block, 4 lanes each) ----
    {
        float* ls = (float*)lp;
        const float4* sv = (const float4*)(s + (size_t)b * NN);
        float4* lv4 = (float4*)ls;
        for (int k = tid; k < NN / 4; k += 256) lv4[k] = sv[k];
        __syncthreads();
        const int o = (chunk << 6) + (tid >> 2);
        const int ch = tid & 3;
        const float x = ls[o];
        const float4* lv = (const float4*)ls;
        int cnt = 0;
        for (int k4 = ch; k4 < NN / 4; k4 += 4) {
            float4 v = lv[k4];
            int kb = k4 << 2;
            cnt += (v.x > x) || (v.x == x && (kb + 0) < o);
            cnt += (v.y > x) || (v.y == x && (kb + 1) < o);
            cnt += (v.z > x) || (v.z == x && (kb + 2) < o);
            cnt += (v.w > x) || (v.w == x && (kb + 3) < o);
        }
        cnt += __shfl_xor(cnt, 1);
        cnt += __shfl_xor(cnt, 2);
        if (ch == 0) {
            A[(size_t)b * NN + cnt] = make_float2(x, 0.f);
            iperm[(size_t)b * NN + cnt] = o;
        }
    }
    batch_barrier(bar, BPB * 1);

    pot_phase(A, B, lp, pd, b, chunk);   // c  (col norm 1)
    batch_barrier(bar, BPB * 2);
    pot_phase(B, A, lp, pd, b, chunk);   // r  (row norm 1)
    batch_barrier(bar, BPB * 3);
    pot_phase(A, B, lp, pd, b, chunk);   // cc (col norm 2)
    batch_barrier(bar, BPB * 4);

    // ---------------- phase 4: top-K output, scatter to original order -----
    {
        const float4* src4 = (const float4*)(B + (size_t)b * NN);
        float4* lp4 = (float4*)lp;
        for (int k = tid; k < NN / 2; k += 256) lp4[k] = src4[k];
        __syncthreads();
        const int w = tid >> 6, ln = tid & 63;
        const int obase = chunk << 6;
        const int o = obase + ln;
        const float x = lp[o].x;
        const float bhi = lp[obase].x + WIN;
        const float blo = lp[obase + OPB - 1].x - WIN;
        int l0 = 0, r0 = NN, l1 = 0, r1 = NN;
#pragma unroll
        for (int it = 0; it < 11; ++it) {
            int m0 = (l0 + r0) >> 1; bool c0 = lp[m0].x < bhi;  r0 = c0 ? m0 : r0; l0 = c0 ? l0 : m0 + 1;
            int m1 = (l1 + r1) >> 1; bool c1 = lp[m1].x <= blo; r1 = c1 ? m1 : r1; l1 = c1 ? l1 : m1 + 1;
        }
        const int lo = l0, hi = l1;
        const bool isTop = (obase + OPB <= KTOP);

        if (isTop) {
            float ad = 0.f, an = 0.f;
            for (int j = lo + w; j < hi; j += 4) {
                float2 p = lp[j];
                float d = x - p.x;
                float t = exp2f(fmaf(-KE * d, d, p.y));
                ad += t;
                an += (j < KTOP) ? t : 0.f;
            }
            pd[w][ln] = ad; pn[w][ln] = an;
            __syncthreads();
            if (w == 0) {
                float den = (pd[0][ln] + pd[1][ln]) + (pd[2][ln] + pd[3][ln]);
                float num = (pn[0][ln] + pn[1][ln]) + (pn[2][ln] + pn[3][ln]);
                int dst = iperm[(size_t)b * NN + o];
                out[(size_t)b * NN + dst] = LN2 * (log2f(num) - log2f(den));
            }
        } else {
            float ad = 0.f;
            for (int j = lo + w; j < hi; j += 4) {
                float2 p = lp[j];
                float d = x - p.x;
                ad += exp2f(fmaf(-KE * d, d, p.y));
            }
            pd[w][ln] = ad;
            const float tK = lp[KTOP - 1].x;
            const float xwm = lp[obase].x;
            const float dwv = tK - xwm;
            const float vb = xwm + sqrtf(fmaf(dwv, dwv, MARG2));
            int l = 0, r = KTOP;
#pragma unroll
            for (int it = 0; it < 8; ++it) {
                int m = (l + r) >> 1; bool c = lp[m].x < vb; r = c ? m : r; l = c ? l : m + 1;
            }
            float mx = -3.4e38f;
            for (int jj = l + w; jj < KTOP; jj += 4) {
                float2 p = lp[jj];
                float d = x - p.x;
                mx = fmaxf(mx, fmaf(-KE * d, d, p.y));
            }
            float ss = 0.f;
            for (int jj = l + w; jj < KTOP; jj += 4) {
                float2 p = lp[jj];
                float d = x - p.x;
                ss += exp2f(fmaf(-KE * d, d, p.y) - mx);
            }
            pn[w][ln] = ss; pm[w][ln] = mx;
            __syncthreads();
            if (w == 0) {
                float den = (pd[0][ln] + pd[1][ln]) + (pd[2][ln] + pd[3][ln]);
                float M = fmaxf(fmaxf(pm[0][ln], pm[1][ln]), fmaxf(pm[2][ln], pm[3][ln]));
                float num = pn[0][ln] * exp2f(pm[0][ln] - M) + pn[1][ln] * exp2f(pm[1][ln] - M)
                          + pn[2][ln] * exp2f(pm[2][ln] - M) + pn[3][ln] * exp2f(pm[3][ln] - M);
                int dst = iperm[(size_t)b * NN + o];
                out[(size_t)b * NN + dst] = LN2 * (M + log2f(num) - log2f(den));
            }
        }
    }
}

extern "C" void kernel_launch(void* const* d_in, const int* in_sizes, int n_in,
                              void* d_out, int out_size, void* d_ws, size_t ws_size,
                              hipStream_t stream) {
    const float* s = (const float*)d_in[0];
    float* out = (float*)d_out;
    const int Bn = in_sizes[0] / NN;              // 32 batches

    float2* A = (float2*)d_ws;                    // ping (value, -log2 pot)
    float2* B = A + (size_t)Bn * NN;              // pong
    int* iperm = (int*)(B + (size_t)Bn * NN);     // inverse permutation
    int* bar = iperm + (size_t)Bn * NN;           // per-batch barrier counters

    // zero barrier counters each launch (graph-legal async memset node)
    hipMemsetAsync(bar, 0, (size_t)Bn * 32 * sizeof(int), stream);

    void* args[] = {(void*)&s, (void*)&A, (void*)&B, (void*)&iperm,
                    (void*)&bar, (void*)&out};
    dim3 grid(Bn * BPB), block(256);
    hipLaunchCooperativeKernel((const void*)fused_k, grid, block, args, 0, stream);
}

// Round 7
// 244.880 us; speedup vs baseline: 1.0479x; 1.0479x over previous
//
#include <hip/hip_runtime.h>

#define NN 2048
#define KTOP 256
#define NBINS 1024
#define WIN 0.25f            // 1000*WIN^2 = 62.5 nats = 90 bits of window margin
#define KEL 1442.6951f       // 1000*log2(e): exp(-1000 d^2) = 2^(-KEL d^2)
#define KEL2 2885.3902f      // 2*KEL
#define LN2 0.69314718f
#define MARG2 0.0625f        // value^2 margin for far-output numerator window

// ---------------------------------------------------------------------------
// Single-dispatch fused Sinkhorn top-K. One block per batch (32 blocks x 1024
// threads); the entire batch lives in LDS, phases separated by __syncthreads
// only — no cross-workgroup sync of any kind (grid.sync and fence-based
// barriers both cost O(100us) on MI355X, measured R3/R6).
//
// Pipeline (all in sorted-descending value space, scatter at the end):
//   sort:   O(n) bucket sort (1024 bins, exact within-bucket rank)
//   c_j  = -log2 sum_i 2^(-KEL(t_i-t_j)^2)            } windowed +-WIN,
//   r_i  = -log2 sum_j 2^(-KEL(t_i-t_j)^2 - c_j)      } terms outside
//   D_j  = -log2 sum_i 2^(-KEL(t_i-t_j)^2 - r_i)      } underflow vs kept
//   out  = ln2*(log2 LSE_{j<K} - log2 LSE_all),  g_j = -KEL(x-t_j)^2 - D_j
// (row potentials r, r2 cancel algebraically in out; verified R1-R5.)
// Inner-loop algebra: g_j = fma(A_j, x, B_j) - q with A=2*KEL*t, B=y-KEL*t^2,
// q=KEL*x^2 -> 3 VALU + 1 native exp2 per term.
// ---------------------------------------------------------------------------
__global__ __launch_bounds__(1024) void fused1_k(const float* __restrict__ s,
                                                 float* __restrict__ out) {
    __shared__ float  T[NN];          // sorted values, descending
    __shared__ float  T2[NN];         // KEL * t^2
    __shared__ float  Y[NN];          // current potential (aliases s-staging)
    __shared__ float2 AB[NN];         // per-phase (A_j, B_j) (aliases VB/IB)
    __shared__ int    IP[NN];         // prefix scratch, then iperm
    __shared__ int    BK[NBINS + 1];  // histogram -> bucket starts
    __shared__ float  RMIN[16], RMAX[16];
    __shared__ int    WLO[16], WHI[16], WNM[16];

    const int b   = blockIdx.x;
    const int tid = threadIdx.x;
    const int w   = tid >> 6;
    const int ln  = tid & 63;

    float* SS = Y;                    // staging alias (dead once scatter done)
    float* VB = (float*)AB;           // bucket-scattered values
    int*   IB = (int*)(VB + NN);      // bucket-scattered original indices

    // ---------------- load + min/max ----------------
    float vmin = 3.4e38f, vmax = -3.4e38f;
    for (int k = tid; k < NN; k += 1024) {
        float v = s[(size_t)b * NN + k];
        SS[k] = v;
        vmin = fminf(vmin, v);
        vmax = fmaxf(vmax, v);
    }
#pragma unroll
    for (int off = 32; off > 0; off >>= 1) {
        vmin = fminf(vmin, __shfl_xor(vmin, off));
        vmax = fmaxf(vmax, __shfl_xor(vmax, off));
    }
    if (ln == 0) { RMIN[w] = vmin; RMAX[w] = vmax; }
    if (tid < NBINS) BK[tid] = 0;
    __syncthreads();
    float wmin = RMIN[0], wmax = RMAX[0];
#pragma unroll
    for (int i = 1; i < 16; ++i) {
        wmin = fminf(wmin, RMIN[i]);
        wmax = fmaxf(wmax, RMAX[i]);
    }
    const float scale = (float)(NBINS - 1) / fmaxf(wmax - wmin, 1e-20f);

    // ---------------- histogram ----------------
    for (int k = tid; k < NN; k += 1024) {
        int bin = (int)((wmax - SS[k]) * scale);
        bin = min(NBINS - 1, max(0, bin));
        atomicAdd(&BK[bin], 1);
    }
    __syncthreads();

    // ---------------- exclusive prefix (Hillis-Steele, ping-pong in IP) ----
    {
        int* P0 = IP;
        int* P1 = IP + NBINS;
        P0[tid] = BK[tid];            // tid < 1024 == NBINS always
        __syncthreads();
        int* srcp = P0; int* dstp = P1;
        for (int off = 1; off < NBINS; off <<= 1) {
            int v = srcp[tid];
            if (tid >= off) v += srcp[tid - off];
            dstp[tid] = v;
            __syncthreads();
            int* tmp = srcp; srcp = dstp; dstp = tmp;
        }
        // inclusive scan now in srcp (= P0 after 10 swaps)
        BK[tid] = tid ? srcp[tid - 1] : 0;
        if (tid == 0) BK[NBINS] = NN;
        __syncthreads();
        int* WS = IP + NBINS;         // working copy for scatter
        WS[tid] = BK[tid];
        __syncthreads();

        // ---------------- scatter by bucket ----------------
        for (int k = tid; k < NN; k += 1024) {
            float v = SS[k];
            int bin = (int)((wmax - v) * scale);
            bin = min(NBINS - 1, max(0, bin));
            int pos = atomicAdd(&WS[bin], 1);
            VB[pos] = v;
            IB[pos] = k;
        }
        __syncthreads();
    }

    // ---------------- exact rank within bucket ----------------
    for (int p = tid; p < NN; p += 1024) {
        float v = VB[p];
        int id = IB[p];
        int bin = (int)((wmax - v) * scale);
        bin = min(NBINS - 1, max(0, bin));
        int blo = BK[bin], bhi = BK[bin + 1];
        int rk = blo;
        for (int m = blo; m < bhi; ++m) {
            float u = VB[m];
            rk += (u > v) || (u == v && IB[m] < id);
        }
        T[rk] = v;                    // T, IP distinct from VB/IB: safe
        IP[rk] = id;                  // prefix scratch regions are dead
    }
    __syncthreads();

    // ---------------- init T2, Y; precompute per-wave windows --------------
    for (int k = tid; k < NN; k += 1024) {
        float t = T[k];
        T2[k] = KEL * t * t;
        Y[k] = 0.f;                   // SS alias dead
    }
    __syncthreads();
    {
        const int base = w << 7;      // wave owns 128 consecutive sorted pos
        const float bhiv = T[base] + WIN;
        const float blov = T[base + 127] - WIN;
        int l0 = 0, r0 = NN, l1 = 0, r1 = NN;
#pragma unroll
        for (int it = 0; it < 12; ++it) {   // 12 iters: exact for size 2049
            int m0 = (l0 + r0) >> 1; bool c0 = T[m0] < bhiv;  r0 = c0 ? m0 : r0; l0 = c0 ? l0 : m0 + 1;
            int m1 = (l1 + r1) >> 1; bool c1 = T[m1] <= blov; r1 = c1 ? m1 : r1; l1 = c1 ? l1 : m1 + 1;
        }
        int lw = 0;
        if (w >= 2) {                 // far waves: numerator slice near vK
            const float vK = T[KTOP - 1];
            const float xm = T[base];
            const float g = vK - xm;
            const float vb = xm + sqrtf(fmaf(g, g, MARG2));
            int l = 0, r = KTOP;
#pragma unroll
            for (int it = 0; it < 9; ++it) {  // exact for size 257
                int m = (l + r) >> 1; bool c = T[m] < vb; r = c ? m : r; l = c ? l : m + 1;
            }
            lw = l;
        }
        if (ln == 0) { WLO[w] = l0; WHI[w] = l1; WNM[w] = lw; }
    }
    __syncthreads();

    const int o0 = (w << 7) + ln;
    const int o1 = o0 + 64;
    const float x0 = T[o0], x1 = T[o1];
    const float q0 = KEL * x0 * x0, q1 = KEL * x1 * x1;
    const int lo = WLO[w], hi = WHI[w];

    // ---------------- three potential phases (c, r, D) ---------------------
    for (int ph = 0; ph < 3; ++ph) {
        for (int k = tid; k < NN; k += 1024)
            AB[k] = make_float2(KEL2 * T[k], Y[k] - T2[k]);
        __syncthreads();
        float a0 = 0.f, a1 = 0.f;
        for (int j = lo; j < hi; ++j) {
            float2 p = AB[j];
            a0 += exp2f(fmaf(p.x, x0, p.y) - q0);
            a1 += exp2f(fmaf(p.x, x1, p.y) - q1);
        }
        Y[o0] = -log2f(a0);
        Y[o1] = -log2f(a1);
        __syncthreads();
    }

    // ---------------- final: top-K LSE ratio, scatter ----------------------
    for (int k = tid; k < NN; k += 1024)
        AB[k] = make_float2(KEL2 * T[k], Y[k] - T2[k]);
    __syncthreads();

    float res0, res1;
    if (w < 2) {
        // outputs 0..255 are exactly the top-K: matching term >= 2^-44 in
        // both num and den -> naive fused windowed sums
        float d0 = 0.f, d1 = 0.f, n0 = 0.f, n1 = 0.f;
        for (int j = lo; j < hi; ++j) {
            float2 p = AB[j];
            float e0 = exp2f(fmaf(p.x, x0, p.y) - q0);
            float e1 = exp2f(fmaf(p.x, x1, p.y) - q1);
            d0 += e0; d1 += e1;
            if (j < KTOP) { n0 += e0; n1 += e1; }
        }
        res0 = LN2 * (log2f(n0) - log2f(d0));
        res1 = LN2 * (log2f(n1) - log2f(d1));
    } else {
        // denominator: windowed naive sum (matching term dominates)
        float d0 = 0.f, d1 = 0.f;
        for (int j = lo; j < hi; ++j) {
            float2 p = AB[j];
            d0 += exp2f(fmaf(p.x, x0, p.y) - q0);
            d1 += exp2f(fmaf(p.x, x1, p.y) - q1);
        }
        // numerator: slice [lw, KTOP) of top-K values, explicit max tracking
        // (its max can be ~ -3.7e4 in log2 units)
        const int lw = WNM[w];
        float m0 = -3.4e38f, m1 = -3.4e38f;
        for (int j = lw; j < KTOP; ++j) {
            float2 p = AB[j];
            m0 = fmaxf(m0, fmaf(p.x, x0, p.y) - q0);
            m1 = fmaxf(m1, fmaf(p.x, x1, p.y) - q1);
        }
        float s0 = 0.f, s1 = 0.f;
        for (int j = lw; j < KTOP; ++j) {
            float2 p = AB[j];
            s0 += exp2f(fmaf(p.x, x0, p.y) - q0 - m0);
            s1 += exp2f(fmaf(p.x, x1, p.y) - q1 - m1);
        }
        res0 = LN2 * (m0 + log2f(s0) - log2f(d0));
        res1 = LN2 * (m1 + log2f(s1) - log2f(d1));
    }
    out[(size_t)b * NN + IP[o0]] = res0;
    out[(size_t)b * NN + IP[o1]] = res1;
}

extern "C" void kernel_launch(void* const* d_in, const int* in_sizes, int n_in,
                              void* d_out, int out_size, void* d_ws, size_t ws_size,
                              hipStream_t stream) {
    const float* s = (const float*)d_in[0];
    float* out = (float*)d_out;
    const int Bn = in_sizes[0] / NN;  // 32 batches

    fused1_k<<<dim3(Bn), dim3(1024), 0, stream>>>(s, out);
}

// Round 8
// 70.249 us; speedup vs baseline: 3.6529x; 3.4859x over previous
//
#include <hip/hip_runtime.h>

#define NN 2048
#define KTOP 256
#define NBINS 1024
#define WIN 0.25f          // value-space window; 1000*WIN^2 = 62.5 nats = 90 bits
#define KE 1442.6951f      // 1000 * log2(e): exp(-1000 d^2) = 2^(-KE d^2)
#define LN2 0.69314718f
#define MARG2 0.0625f      // value^2 margin for top-K numerator window
#define OPB 64             // outputs per block (pot/topk)

// ---------------------------------------------------------------------------
// O(n) bucket sort, one block per batch (32 blocks x 1024 threads).
// histogram(1024 bins) -> prefix scan -> scatter -> exact rank within bucket.
// Writes (value, 0) pairs sorted descending + inverse permutation.
// Low occupancy is fine: O(n) work, ~2-4 us total (vs ~25 us O(n^2) rank sort).
// ---------------------------------------------------------------------------
__global__ __launch_bounds__(1024) void bsort_k(const float* __restrict__ s,
                                                float2* __restrict__ A,
                                                int* __restrict__ iperm) {
    __shared__ float SS[NN];
    __shared__ float VB[NN];
    __shared__ int   IB[NN];
    __shared__ int   BK[NBINS + 1];
    __shared__ int   PP[2][NBINS];
    __shared__ float RMIN[16], RMAX[16];

    const int b = blockIdx.x;
    const int tid = threadIdx.x;
    const int w = tid >> 6, ln = tid & 63;

    float vmin = 3.4e38f, vmax = -3.4e38f;
    for (int k = tid; k < NN; k += 1024) {
        float v = s[(size_t)b * NN + k];
        SS[k] = v;
        vmin = fminf(vmin, v);
        vmax = fmaxf(vmax, v);
    }
#pragma unroll
    for (int off = 32; off > 0; off >>= 1) {
        vmin = fminf(vmin, __shfl_xor(vmin, off));
        vmax = fmaxf(vmax, __shfl_xor(vmax, off));
    }
    if (ln == 0) { RMIN[w] = vmin; RMAX[w] = vmax; }
    BK[tid] = 0;                          // tid < 1024 == NBINS
    __syncthreads();
    float wmin = RMIN[0], wmax = RMAX[0];
#pragma unroll
    for (int i = 1; i < 16; ++i) {
        wmin = fminf(wmin, RMIN[i]);
        wmax = fmaxf(wmax, RMAX[i]);
    }
    const float scale = (float)(NBINS - 1) / fmaxf(wmax - wmin, 1e-20f);

    for (int k = tid; k < NN; k += 1024) {
        int bin = (int)((wmax - SS[k]) * scale);
        bin = min(NBINS - 1, max(0, bin));
        atomicAdd(&BK[bin], 1);
    }
    __syncthreads();

    // Hillis-Steele inclusive scan, ping-pong
    PP[0][tid] = BK[tid];
    __syncthreads();
    int sel = 0;
    for (int off = 1; off < NBINS; off <<= 1) {
        int v = PP[sel][tid];
        if (tid >= off) v += PP[sel][tid - off];
        PP[sel ^ 1][tid] = v;
        __syncthreads();
        sel ^= 1;
    }
    BK[tid] = tid ? PP[sel][tid - 1] : 0;   // exclusive starts
    if (tid == 0) BK[NBINS] = NN;
    __syncthreads();
    int* WS = PP[sel ^ 1];
    WS[tid] = BK[tid];
    __syncthreads();

    for (int k = tid; k < NN; k += 1024) {
        float v = SS[k];
        int bin = (int)((wmax - v) * scale);
        bin = min(NBINS - 1, max(0, bin));
        int pos = atomicAdd(&WS[bin], 1);
        VB[pos] = v;
        IB[pos] = k;
    }
    __syncthreads();

    for (int p = tid; p < NN; p += 1024) {
        float v = VB[p];
        int id = IB[p];
        int bin = (int)((wmax - v) * scale);
        bin = min(NBINS - 1, max(0, bin));
        int blo = BK[bin], bhi = BK[bin + 1];
        int rk = blo;
        for (int m = blo; m < bhi; ++m) {
            float u = VB[m];
            rk += (u > v) || (u == v && IB[m] < id);
        }
        A[(size_t)b * NN + rk] = make_float2(v, 0.f);
        iperm[(size_t)b * NN + rk] = id;
    }
}

// ---------------------------------------------------------------------------
// Potential pass: pout[o] = (t_o, -log2 sum_j 2^(-KE*(t_o-t_j)^2 + y_j)).
// Block = 4 waves x 64 outputs; block-union window split across the 4 waves
// (stride 4), partials combined via LDS. All lp reads wave-broadcast.
// ---------------------------------------------------------------------------
__global__ __launch_bounds__(256) void pot_k(const float2* __restrict__ pin,
                                             float2* __restrict__ pout) {
    __shared__ float2 lp[NN];
    __shared__ float part[4][OPB];
    const int b = blockIdx.x >> 5;                // 32 blocks/batch
    const int obase = (blockIdx.x & 31) << 6;     // 64 outputs/block
    const int tid = threadIdx.x;
    const int w = tid >> 6, ln = tid & 63;
    const float4* src4 = (const float4*)(pin + (size_t)b * NN);
    float4* lp4 = (float4*)lp;
    for (int k = tid; k < NN / 2; k += 256) lp4[k] = src4[k];
    __syncthreads();
    const int o = obase + ln;
    const float x = lp[o].x;
    const float bhi = lp[obase].x + WIN;
    const float blo = lp[obase + OPB - 1].x - WIN;
    int l0 = 0, r0 = NN, l1 = 0, r1 = NN;
#pragma unroll
    for (int it = 0; it < 11; ++it) {
        int m0 = (l0 + r0) >> 1; bool c0 = lp[m0].x < bhi;  r0 = c0 ? m0 : r0; l0 = c0 ? l0 : m0 + 1;
        int m1 = (l1 + r1) >> 1; bool c1 = lp[m1].x <= blo; r1 = c1 ? m1 : r1; l1 = c1 ? l1 : m1 + 1;
    }
    const int lo = l0, hi = l1;
    float a0 = 0.f, a1 = 0.f;
    int j = lo + w;
    for (; j + 4 < hi; j += 8) {
        float2 p0 = lp[j], p1 = lp[j + 4];
        float d0 = x - p0.x, d1 = x - p1.x;
        a0 += exp2f(fmaf(-KE * d0, d0, p0.y));
        a1 += exp2f(fmaf(-KE * d1, d1, p1.y));
    }
    if (j < hi) { float2 p = lp[j]; float d = x - p.x; a0 += exp2f(fmaf(-KE * d, d, p.y)); }
    part[w][ln] = a0 + a1;
    __syncthreads();
    if (w == 0) {
        float a = (part[0][ln] + part[1][ln]) + (part[2][ln] + part[3][ln]);
        pout[(size_t)b * NN + o] = make_float2(x, -log2f(a));
    }
}

// ---------------------------------------------------------------------------
// Final pass (sorted space, scatter to original order):
//   out = ln2 * ( log2 LSE_{j<K}(g) - log2 LSE_j(g) ),  g = -KE d^2 + y_j.
// ---------------------------------------------------------------------------
__global__ __launch_bounds__(256) void topk_k(const float2* __restrict__ pin,
                                              const int* __restrict__ iperm,
                                              float* __restrict__ out) {
    __shared__ float2 lp[NN];
    __shared__ float pd[4][OPB];
    __shared__ float pn[4][OPB];
    __shared__ float pm[4][OPB];
    const int b = blockIdx.x >> 5;
    const int obase = (blockIdx.x & 31) << 6;
    const int tid = threadIdx.x;
    const int w = tid >> 6, ln = tid & 63;
    const float4* src4 = (const float4*)(pin + (size_t)b * NN);
    float4* lp4 = (float4*)lp;
    for (int k = tid; k < NN / 2; k += 256) lp4[k] = src4[k];
    const int o = obase + ln;
    int dst = 0;
    if (w == 0) dst = iperm[(size_t)b * NN + o];
    __syncthreads();
    const float x = lp[o].x;
    const float bhi = lp[obase].x + WIN;
    const float blo = lp[obase + OPB - 1].x - WIN;
    int l0 = 0, r0 = NN, l1 = 0, r1 = NN;
#pragma unroll
    for (int it = 0; it < 11; ++it) {
        int m0 = (l0 + r0) >> 1; bool c0 = lp[m0].x < bhi;  r0 = c0 ? m0 : r0; l0 = c0 ? l0 : m0 + 1;
        int m1 = (l1 + r1) >> 1; bool c1 = lp[m1].x <= blo; r1 = c1 ? m1 : r1; l1 = c1 ? l1 : m1 + 1;
    }
    const int lo = l0, hi = l1;
    const bool isTop = (obase + OPB <= KTOP);

    if (isTop) {
        float ad = 0.f, an = 0.f;
        for (int j = lo + w; j < hi; j += 4) {
            float2 p = lp[j];
            float d = x - p.x;
            float t = exp2f(fmaf(-KE * d, d, p.y));
            ad += t;
            an += (j < KTOP) ? t : 0.f;
        }
        pd[w][ln] = ad; pn[w][ln] = an;
        __syncthreads();
        if (w == 0) {
            float den = (pd[0][ln] + pd[1][ln]) + (pd[2][ln] + pd[3][ln]);
            float num = (pn[0][ln] + pn[1][ln]) + (pn[2][ln] + pn[3][ln]);
            out[(size_t)b * NN + dst] = LN2 * (log2f(num) - log2f(den));
        }
    } else {
        float ad = 0.f;
        for (int j = lo + w; j < hi; j += 4) {
            float2 p = lp[j];
            float d = x - p.x;
            ad += exp2f(fmaf(-KE * d, d, p.y));
        }
        pd[w][ln] = ad;
        const float tK = lp[KTOP - 1].x;
        const float xwm = lp[obase].x;
        const float dwv = tK - xwm;
        const float vb = xwm + sqrtf(fmaf(dwv, dwv, MARG2));
        int l = 0, r = KTOP;
#pragma unroll
        for (int it = 0; it < 8; ++it) {
            int m = (l + r) >> 1; bool c = lp[m].x < vb; r = c ? m : r; l = c ? l : m + 1;
        }
        float mx = -3.4e38f;
        for (int jj = l + w; jj < KTOP; jj += 4) {
            float2 p = lp[jj];
            float d = x - p.x;
            mx = fmaxf(mx, fmaf(-KE * d, d, p.y));
        }
        float ss = 0.f;
        for (int jj = l + w; jj < KTOP; jj += 4) {
            float2 p = lp[jj];
            float d = x - p.x;
            ss += exp2f(fmaf(-KE * d, d, p.y) - mx);
        }
        pn[w][ln] = ss; pm[w][ln] = mx;
        __syncthreads();
        if (w == 0) {
            float den = (pd[0][ln] + pd[1][ln]) + (pd[2][ln] + pd[3][ln]);
            float M = fmaxf(fmaxf(pm[0][ln], pm[1][ln]), fmaxf(pm[2][ln], pm[3][ln]));
            float num = pn[0][ln] * exp2f(pm[0][ln] - M) + pn[1][ln] * exp2f(pm[1][ln] - M)
                      + pn[2][ln] * exp2f(pm[2][ln] - M) + pn[3][ln] * exp2f(pm[3][ln] - M);
            out[(size_t)b * NN + dst] = LN2 * (M + log2f(num) - log2f(den));
        }
    }
}

extern "C" void kernel_launch(void* const* d_in, const int* in_sizes, int n_in,
                              void* d_out, int out_size, void* d_ws, size_t ws_size,
                              hipStream_t stream) {
    const float* s = (const float*)d_in[0];
    float* out = (float*)d_out;
    const int Bn = in_sizes[0] / NN;              // 32 batches

    float2* A = (float2*)d_ws;                    // ping (value, -log2 pot)
    float2* B = A + (size_t)Bn * NN;              // pong
    int* iperm = (int*)(B + (size_t)Bn * NN);     // inverse permutation

    bsort_k<<<Bn, 1024, 0, stream>>>(s, A, iperm);          // O(n) sort
    pot_k<<<Bn * 32, 256, 0, stream>>>(A, B);               // c  (col norm 1)
    pot_k<<<Bn * 32, 256, 0, stream>>>(B, A);               // r  (row norm 1)
    pot_k<<<Bn * 32, 256, 0, stream>>>(A, B);               // cc (col norm 2)
    topk_k<<<Bn * 32, 256, 0, stream>>>(B, iperm, out);     // output + scatter
}